// Round 1
// baseline (2896.983 us; speedup 1.0000x reference)
//
#include <hip/hip_runtime.h>
#include <cstdint>
#include <cstddef>

// ---- problem constants (fixed by the reference) ----
#define D_MODEL 2048
#define D_INNER 4096
#define D_IN2   8192            // 2*D_INNER
#define D_STATE 16
#define D_CONVK 4
#define DT_RANK 128
#define BATCH   2
#define SEQLEN  1024
#define BL      (BATCH*SEQLEN)  // 2048 rows for all GEMMs
#define XDBL_N  (DT_RANK + 2*D_STATE)  // 160

// ---- tiled fp32 GEMM: C[m,n] = sum_k A[m,k]*W[n,k] (+ optional bias+softplus) ----
constexpr int BT = 128;  // M/N tile
constexpr int KT = 16;   // K tile

__device__ __forceinline__ float softplus_f(float v) {
    return (v > 20.f) ? v : log1pf(__expf(v));
}
__device__ __forceinline__ float silu_f(float v) {
    return v / (1.f + __expf(-v));
}

// EPI: 0 = none, 1 = bias + softplus
template<int EPI>
__global__ __launch_bounds__(256, 2)
void gemm_tn(const float* __restrict__ A, int lda,
             const float* __restrict__ W,
             const float* __restrict__ bias,
             float* __restrict__ C,
             int M, int N, int K)
{
    __shared__ float sA[KT][BT + 4];
    __shared__ float sW[KT][BT + 4];
    const int tid = threadIdx.x;          // 0..255
    const int bm  = blockIdx.y * BT;
    const int bn  = blockIdx.x * BT;

    // loader mapping: 2 float4 per matrix per thread per K-tile
    const int lrow = tid >> 2;            // 0..63
    const int lcol = (tid & 3) * 4;       // 0,4,8,12

    // compute mapping: 16x16 threads, 8x8 microtile (split 4+4 at +64)
    const int tx = tid & 15;
    const int ty = tid >> 4;

    float acc[8][8];
#pragma unroll
    for (int i = 0; i < 8; i++)
#pragma unroll
        for (int j = 0; j < 8; j++) acc[i][j] = 0.f;

    const int  wr0  = bn + lrow;
    const int  wr1  = bn + lrow + 64;
    const bool w0ok = wr0 < N;
    const bool w1ok = wr1 < N;
    const float4 z4 = make_float4(0.f, 0.f, 0.f, 0.f);

    for (int k0 = 0; k0 < K; k0 += KT) {
        // global loads (M=2048 is always a multiple of BT; K multiple of KT; only N can be ragged)
        const float4 a0 = *(const float4*)(A + (size_t)(bm + lrow)      * lda + (k0 + lcol));
        const float4 a1 = *(const float4*)(A + (size_t)(bm + lrow + 64) * lda + (k0 + lcol));
        const float4 w0 = w0ok ? *(const float4*)(W + (size_t)wr0 * K + (k0 + lcol)) : z4;
        const float4 w1 = w1ok ? *(const float4*)(W + (size_t)wr1 * K + (k0 + lcol)) : z4;
        __syncthreads();   // previous compute phase done before overwriting LDS
        sA[lcol + 0][lrow]      = a0.x; sA[lcol + 1][lrow]      = a0.y;
        sA[lcol + 2][lrow]      = a0.z; sA[lcol + 3][lrow]      = a0.w;
        sA[lcol + 0][lrow + 64] = a1.x; sA[lcol + 1][lrow + 64] = a1.y;
        sA[lcol + 2][lrow + 64] = a1.z; sA[lcol + 3][lrow + 64] = a1.w;
        sW[lcol + 0][lrow]      = w0.x; sW[lcol + 1][lrow]      = w0.y;
        sW[lcol + 2][lrow]      = w0.z; sW[lcol + 3][lrow]      = w0.w;
        sW[lcol + 0][lrow + 64] = w1.x; sW[lcol + 1][lrow + 64] = w1.y;
        sW[lcol + 2][lrow + 64] = w1.z; sW[lcol + 3][lrow + 64] = w1.w;
        __syncthreads();
#pragma unroll
        for (int k = 0; k < KT; k++) {
            float a[8], b[8];
            *(float4*)(a)     = *(const float4*)(&sA[k][ty * 4]);
            *(float4*)(a + 4) = *(const float4*)(&sA[k][64 + ty * 4]);
            *(float4*)(b)     = *(const float4*)(&sW[k][tx * 4]);
            *(float4*)(b + 4) = *(const float4*)(&sW[k][64 + tx * 4]);
#pragma unroll
            for (int i = 0; i < 8; i++)
#pragma unroll
                for (int j = 0; j < 8; j++)
                    acc[i][j] = fmaf(a[i], b[j], acc[i][j]);
        }
    }

#pragma unroll
    for (int i = 0; i < 8; i++) {
        const int r = bm + ty * 4 + (i & 3) + ((i >> 2) * 64);
#pragma unroll
        for (int jj = 0; jj < 2; jj++) {
            const int c = bn + tx * 4 + jj * 64;
            if (c < N) {   // N is a multiple of 4 and c is 4-aligned -> whole float4 in-bounds
                float4 v;
                v.x = acc[i][jj * 4 + 0]; v.y = acc[i][jj * 4 + 1];
                v.z = acc[i][jj * 4 + 2]; v.w = acc[i][jj * 4 + 3];
                if (EPI == 1) {
                    v.x = softplus_f(v.x + bias[c + 0]);
                    v.y = softplus_f(v.y + bias[c + 1]);
                    v.z = softplus_f(v.z + bias[c + 2]);
                    v.w = softplus_f(v.w + bias[c + 3]);
                }
                *(float4*)(C + (size_t)r * N + c) = v;
            }
        }
    }
}

// ---- causal depthwise conv1d (K=4) + SiLU; reads x half of xz, writes x_act ----
__global__ __launch_bounds__(256)
void conv_silu_kernel(const float* __restrict__ xz,
                      const float* __restrict__ cw,   // [D_INNER,4]
                      const float* __restrict__ cb,   // [D_INNER]
                      float* __restrict__ x_act)      // [BL, D_INNER]
{
    const int idx = blockIdx.x * 256 + threadIdx.x;   // over BL*D_INNER
    const int d  = idx & (D_INNER - 1);
    const int bl = idx >> 12;                         // / D_INNER
    const int l  = bl & (SEQLEN - 1);
    const int b  = bl >> 10;
    const float* xb = xz + (size_t)b * SEQLEN * D_IN2 + d;
    float acc = cb[d];
#pragma unroll
    for (int k = 0; k < D_CONVK; k++) {
        const int ll = l + k - (D_CONVK - 1);
        if (ll >= 0) acc = fmaf(xb[(size_t)ll * D_IN2], cw[d * D_CONVK + k], acc);
    }
    x_act[idx] = silu_f(acc);
}

// ---- selective scan: 16 lanes per (b,d) channel, one lane per state n ----
// Fuses D-skip and z-gating; writes y in place over x_act.
#define SCAN_T 16
__global__ __launch_bounds__(256)
void scan_kernel(const float* __restrict__ x_act,  // [BL, D_INNER] (input x)
                 float* __restrict__ y,            // [BL, D_INNER] (may alias x_act)
                 const float* __restrict__ dt,     // [BL, D_INNER]
                 const float* __restrict__ xdbl,   // [BL, 160]; B at +128, C at +144
                 const float* __restrict__ xz,     // [BL, 8192]; z at +4096
                 const float* __restrict__ A_log,  // [D_INNER, 16]
                 const float* __restrict__ Dvec)   // [D_INNER]
{
    const int ch0 = blockIdx.x * 16;       // 16 channels per block
    const int b   = ch0 / D_INNER;
    const int d0  = ch0 % D_INNER;
    const int tid = threadIdx.x;
    const int g   = tid >> 4;              // channel-in-block 0..15
    const int n   = tid & 15;              // state index
    const int d   = d0 + g;

    const float An = -expf(A_log[d * D_STATE + n]);
    const float Dd = Dvec[d];
    float h = 0.f;

    __shared__ float s_x [SCAN_T][16];
    __shared__ float s_dt[SCAN_T][16];
    __shared__ float s_z [SCAN_T][16];
    __shared__ float s_B [SCAN_T][16];
    __shared__ float s_C [SCAN_T][16];
    __shared__ float s_y [SCAN_T][16];

    const int lt = tid >> 4;   // time-in-chunk for the loader
    const int ld = tid & 15;   // channel/state for the loader

    for (int l0 = 0; l0 < SEQLEN; l0 += SCAN_T) {
        const size_t bl = (size_t)(b * SEQLEN + l0 + lt);
        __syncthreads();  // previous chunk's s_y fully written out
        s_x [lt][ld] = x_act[bl * D_INNER + d0 + ld];
        s_dt[lt][ld] = dt   [bl * D_INNER + d0 + ld];
        s_z [lt][ld] = xz   [bl * D_IN2 + D_INNER + d0 + ld];
        s_B [lt][ld] = xdbl [bl * XDBL_N + DT_RANK + ld];
        s_C [lt][ld] = xdbl [bl * XDBL_N + DT_RANK + D_STATE + ld];
        __syncthreads();
#pragma unroll 4
        for (int t = 0; t < SCAN_T; t++) {
            const float xv  = s_x [t][g];
            const float dtv = s_dt[t][g];
            const float Bn  = s_B [t][n];
            const float Cn  = s_C [t][n];
            const float dA  = __expf(dtv * An);
            h = fmaf(h, dA, dtv * Bn * xv);
            float p = h * Cn;
            p += __shfl_xor(p, 1, 16);
            p += __shfl_xor(p, 2, 16);
            p += __shfl_xor(p, 4, 16);
            p += __shfl_xor(p, 8, 16);
            if (n == 0) {
                const float zv = s_z[t][g];
                s_y[t][g] = fmaf(xv, Dd, p) * silu_f(zv);
            }
        }
        __syncthreads();
        y[bl * D_INNER + d0 + ld] = s_y[lt][ld];
    }
}

extern "C" void kernel_launch(void* const* d_in, const int* in_sizes, int n_in,
                              void* d_out, int out_size, void* d_ws, size_t ws_size,
                              hipStream_t stream)
{
    const float* hidden     = (const float*)d_in[0];
    const float* in_proj_w  = (const float*)d_in[1];
    const float* conv_w     = (const float*)d_in[2];
    const float* conv_b     = (const float*)d_in[3];
    const float* x_proj_w   = (const float*)d_in[4];
    const float* dt_proj_w  = (const float*)d_in[5];
    const float* dt_proj_b  = (const float*)d_in[6];
    const float* A_log      = (const float*)d_in[7];
    const float* Dvec       = (const float*)d_in[8];
    const float* out_proj_w = (const float*)d_in[9];
    float* out = (float*)d_out;

    // workspace layout (fp32): xz 64MiB | x_act 32MiB | x_dbl 1.25MiB | dt 32MiB
    char* ws = (char*)d_ws;
    float* xz    = (float*)(ws);
    float* x_act = (float*)(ws + (size_t)BL * D_IN2 * 4);
    float* x_dbl = (float*)(ws + (size_t)BL * D_IN2 * 4 + (size_t)BL * D_INNER * 4);
    float* dtbuf = (float*)(ws + (size_t)BL * D_IN2 * 4 + (size_t)BL * D_INNER * 4
                               + (size_t)BL * XDBL_N * 4);

    const dim3 blk(256);

    // 1) in_proj: xz[BL, 8192] = hidden[BL,2048] @ in_proj_w[8192,2048]^T
    gemm_tn<0><<<dim3(D_IN2 / BT, BL / BT), blk, 0, stream>>>(
        hidden, D_MODEL, in_proj_w, nullptr, xz, BL, D_IN2, D_MODEL);

    // 2) depthwise causal conv + SiLU -> x_act[BL, 4096]
    conv_silu_kernel<<<dim3((BL * D_INNER) / 256), blk, 0, stream>>>(
        xz, conv_w, conv_b, x_act);

    // 3) x_proj: x_dbl[BL, 160] = x_act @ x_proj_w[160,4096]^T
    gemm_tn<0><<<dim3((XDBL_N + BT - 1) / BT, BL / BT), blk, 0, stream>>>(
        x_act, D_INNER, x_proj_w, nullptr, x_dbl, BL, XDBL_N, D_INNER);

    // 4) dt_proj + bias + softplus: dt[BL, 4096] = softplus(x_dbl[:, :128] @ dt_proj_w^T + b)
    gemm_tn<1><<<dim3(D_INNER / BT, BL / BT), blk, 0, stream>>>(
        x_dbl, XDBL_N, dt_proj_w, dt_proj_b, dtbuf, BL, D_INNER, DT_RANK);

    // 5) selective scan + D-skip + z-gating (y overwrites x_act in place)
    scan_kernel<<<dim3((BATCH * D_INNER) / 16), blk, 0, stream>>>(
        x_act, x_act, dtbuf, x_dbl, xz, A_log, Dvec);

    // 6) out_proj: out[BL, 2048] = y @ out_proj_w[2048,4096]^T
    gemm_tn<0><<<dim3(D_MODEL / BT, BL / BT), blk, 0, stream>>>(
        x_act, D_INNER, out_proj_w, nullptr, out, BL, D_MODEL, D_INNER);
}

// Round 2
// 739.124 us; speedup vs baseline: 3.9195x; 3.9195x over previous
//
#include <hip/hip_runtime.h>
#include <cstdint>
#include <cstddef>

// ---- problem constants ----
#define D_MODEL 2048
#define D_INNER 4096
#define D_IN2   8192
#define D_STATE 16
#define D_CONVK 4
#define DT_RANK 128
#define BATCH   2
#define SEQLEN  1024
#define BL      (BATCH*SEQLEN)
#define XDBL_N  (DT_RANK + 2*D_STATE)   // 160
#define XPW_NPAD 256                    // x_proj N padded to 256
#define XPROJ_SPLITS 8

typedef short  s8v  __attribute__((ext_vector_type(8)));   // 8 bf16 in 4 VGPRs
typedef float  f4v  __attribute__((ext_vector_type(4)));

__device__ __forceinline__ float softplus_f(float v) {
    return (v > 20.f) ? v : log1pf(__expf(v));
}
__device__ __forceinline__ float silu_f(float v) {
    return v / (1.f + __expf(-v));
}
__device__ __forceinline__ float bf2f(short s) {
    return __uint_as_float(((uint32_t)(uint16_t)s) << 16);
}
__device__ __forceinline__ uint16_t f2bf(float f) {   // round-to-nearest-even (benign values)
    uint32_t u = __float_as_uint(f);
    return (uint16_t)((u + 0x7FFFu + ((u >> 16) & 1u)) >> 16);
}
__device__ __forceinline__ uint32_t packbf(float lo, float hi) {
    return ((uint32_t)f2bf(hi) << 16) | (uint32_t)f2bf(lo);
}

// async global->LDS, 16B per lane; LDS dest is wave-uniform base + lane*16
#define GLD16(gp, lp)                                                          \
    __builtin_amdgcn_global_load_lds(                                          \
        (const __attribute__((address_space(1))) void*)(gp),                   \
        (__attribute__((address_space(3))) void*)(lp), 16, 0, 0)

// ---- fp32 -> bf16 cast, 8 elems/thread ----
__global__ __launch_bounds__(256)
void cast_bf16_kernel(const float* __restrict__ in, uint32_t* __restrict__ out, int n8)
{
    const int i = blockIdx.x * 256 + threadIdx.x;
    if (i >= n8) return;
    const float4 a = ((const float4*)in)[i * 2];
    const float4 b = ((const float4*)in)[i * 2 + 1];
    uint4 o;
    o.x = packbf(a.x, a.y); o.y = packbf(a.z, a.w);
    o.z = packbf(b.x, b.y); o.w = packbf(b.z, b.w);
    ((uint4*)out)[i] = o;
}

// ---- bf16 MFMA GEMM: C[m,n] = sum_k A[m,k] * W[n,k]  (C = A * W^T) ----
// 128x128 block tile, BK=32, 4 waves (2x2 of 64x64), 16x16x32 bf16 MFMA.
// EPI: 0 = plain fp32 store, 1 = softplus(v + bias[n]).
// Split-K via gridDim.z: block z handles k in [z*kchunk, z*kchunk+kchunk),
// writing to C + z*M*ldc.
template<int EPI>
__global__ __launch_bounds__(256)
void gemm_bf16_mfma(const short* __restrict__ A, int lda,
                    const short* __restrict__ W, int ldw,
                    const float* __restrict__ bias,
                    float* __restrict__ C, int ldc,
                    int M, int N, int K, int kchunk)
{
    __shared__ short sA[128 * 32];   // 8 KB, packed row-major [row][32]
    __shared__ short sW[128 * 32];

    const int tid = threadIdx.x;
    const int w   = tid >> 6;        // wave 0..3
    const int L   = tid & 63;        // lane
    const int bm  = blockIdx.y * 128;
    const int bn  = blockIdx.x * 128;
    const int k0  = blockIdx.z * kchunk;
    const int k1  = k0 + kchunk;
    C += (size_t)blockIdx.z * M * ldc;

    // staging: wave w stages LDS chunks {2w, 2w+1} of each tile (1 KB each = 16 rows)
    const int qa0 = 2 * w, qa1 = 2 * w + 1;
    const int srow = L >> 2;          // 0..15 row within chunk
    const int scol = (L & 3) * 8;     // bf16 element offset within row

    const short* Ag0 = A + (size_t)(bm + qa0 * 16 + srow) * lda + scol;
    const short* Ag1 = A + (size_t)(bm + qa1 * 16 + srow) * lda + scol;
    const short* Wg0 = W + (size_t)(bn + qa0 * 16 + srow) * ldw + scol;
    const short* Wg1 = W + (size_t)(bn + qa1 * 16 + srow) * ldw + scol;

    // compute mapping: wave quadrant (wm, wn), lane -> (col16, quad)
    const int wm = (w >> 1) * 64;
    const int wn = (w & 1) * 64;
    const int cl = L & 15;
    const int qd = L >> 4;

    f4v acc[4][4];
#pragma unroll
    for (int i = 0; i < 4; i++)
#pragma unroll
        for (int j = 0; j < 4; j++) acc[i][j] = (f4v){0.f, 0.f, 0.f, 0.f};

    for (int k = k0; k < k1; k += 32) {
        GLD16(Ag0 + k, &sA[qa0 * 512]);
        GLD16(Ag1 + k, &sA[qa1 * 512]);
        GLD16(Wg0 + k, &sW[qa0 * 512]);
        GLD16(Wg1 + k, &sW[qa1 * 512]);
        __syncthreads();   // drains vmcnt -> staged data visible

        s8v a[4], b[4];
#pragma unroll
        for (int mt = 0; mt < 4; mt++)
            a[mt] = *(const s8v*)&sA[(wm + mt * 16 + cl) * 32 + qd * 8];
#pragma unroll
        for (int nt = 0; nt < 4; nt++)
            b[nt] = *(const s8v*)&sW[(wn + nt * 16 + cl) * 32 + qd * 8];
#pragma unroll
        for (int mt = 0; mt < 4; mt++)
#pragma unroll
            for (int nt = 0; nt < 4; nt++)
                acc[mt][nt] = __builtin_amdgcn_mfma_f32_16x16x32_bf16(
                    a[mt], b[nt], acc[mt][nt], 0, 0, 0);
        __syncthreads();   // all frag reads done before next stage overwrites
    }

    // epilogue: C/D layout col = lane&15, row = quad*4 + reg
#pragma unroll
    for (int mt = 0; mt < 4; mt++) {
        const int row0 = bm + wm + mt * 16 + qd * 4;
#pragma unroll
        for (int nt = 0; nt < 4; nt++) {
            const int col = bn + wn + nt * 16 + cl;
#pragma unroll
            for (int r = 0; r < 4; r++) {
                float v = acc[mt][nt][r];
                if (EPI == 1) v = softplus_f(v + bias[col]);
                C[(size_t)(row0 + r) * ldc + col] = v;
            }
        }
    }
}

// ---- causal depthwise conv1d (K=4) + SiLU; reads x half of xz (fp32), writes bf16 ----
__global__ __launch_bounds__(256)
void conv_silu_kernel(const float* __restrict__ xz,
                      const float* __restrict__ cw,
                      const float* __restrict__ cb,
                      short* __restrict__ x_bf)
{
    const int idx = blockIdx.x * 256 + threadIdx.x;   // over BL*D_INNER
    const int d  = idx & (D_INNER - 1);
    const int bl = idx >> 12;
    const int l  = bl & (SEQLEN - 1);
    const int b  = bl >> 10;
    const float* xb = xz + (size_t)b * SEQLEN * D_IN2 + d;
    float acc = cb[d];
#pragma unroll
    for (int k = 0; k < D_CONVK; k++) {
        const int ll = l + k - (D_CONVK - 1);
        if (ll >= 0) acc = fmaf(xb[(size_t)ll * D_IN2], cw[d * D_CONVK + k], acc);
    }
    x_bf[idx] = (short)f2bf(silu_f(acc));
}

// ---- reduce x_proj split-K partials -> x_dbl fp32 + bf16 ----
__global__ __launch_bounds__(256)
void reduce_xdbl_kernel(const float* __restrict__ P,   // [8][BL][256]
                        float* __restrict__ xf,        // [BL][160]
                        short* __restrict__ xb)        // [BL][160]
{
    const int idx = blockIdx.x * 256 + threadIdx.x;
    if (idx >= BL * XDBL_N) return;
    const int m = idx / XDBL_N;
    const int n = idx - m * XDBL_N;
    float s = 0.f;
#pragma unroll
    for (int z = 0; z < XPROJ_SPLITS; z++)
        s += P[(size_t)z * BL * XPW_NPAD + (size_t)m * XPW_NPAD + n];
    xf[idx] = s;
    xb[idx] = (short)f2bf(s);
}

// ---- selective scan: 16 lanes per (b,d) channel; fuses D-skip + z-gating ----
#define SCAN_T 16
__global__ __launch_bounds__(256)
void scan_kernel(const short* __restrict__ x_bf,   // [BL, D_INNER] bf16
                 short* __restrict__ y_bf,         // [BL, D_INNER] bf16 out
                 const float* __restrict__ dt,     // [BL, D_INNER]
                 const float* __restrict__ xdbl,   // [BL, 160]; B at +128, C at +144
                 const float* __restrict__ xz,     // [BL, 8192]; z at +4096
                 const float* __restrict__ A_log,
                 const float* __restrict__ Dvec)
{
    const int ch0 = blockIdx.x * 16;
    const int b   = ch0 / D_INNER;
    const int d0  = ch0 % D_INNER;
    const int tid = threadIdx.x;
    const int g   = tid >> 4;
    const int n   = tid & 15;
    const int d   = d0 + g;

    const float An = -expf(A_log[d * D_STATE + n]);
    const float Dd = Dvec[d];
    float h = 0.f;

    __shared__ float s_x [SCAN_T][16];
    __shared__ float s_dt[SCAN_T][16];
    __shared__ float s_z [SCAN_T][16];
    __shared__ float s_B [SCAN_T][16];
    __shared__ float s_C [SCAN_T][16];
    __shared__ float s_y [SCAN_T][16];

    const int lt = tid >> 4;
    const int ld = tid & 15;

    for (int l0 = 0; l0 < SEQLEN; l0 += SCAN_T) {
        const size_t bl = (size_t)(b * SEQLEN + l0 + lt);
        __syncthreads();
        s_x [lt][ld] = bf2f(x_bf[bl * D_INNER + d0 + ld]);
        s_dt[lt][ld] = dt   [bl * D_INNER + d0 + ld];
        s_z [lt][ld] = xz   [bl * D_IN2 + D_INNER + d0 + ld];
        s_B [lt][ld] = xdbl [bl * XDBL_N + DT_RANK + ld];
        s_C [lt][ld] = xdbl [bl * XDBL_N + DT_RANK + D_STATE + ld];
        __syncthreads();
#pragma unroll 4
        for (int t = 0; t < SCAN_T; t++) {
            const float xv  = s_x [t][g];
            const float dtv = s_dt[t][g];
            const float dA  = __expf(dtv * An);
            h = fmaf(h, dA, dtv * s_B[t][n] * xv);
            float p = h * s_C[t][n];
            p += __shfl_xor(p, 1, 16);
            p += __shfl_xor(p, 2, 16);
            p += __shfl_xor(p, 4, 16);
            p += __shfl_xor(p, 8, 16);
            if (n == 0) s_y[t][g] = fmaf(xv, Dd, p) * silu_f(s_z[t][g]);
        }
        __syncthreads();
        y_bf[bl * D_INNER + d0 + ld] = (short)f2bf(s_y[lt][ld]);
    }
}

extern "C" void kernel_launch(void* const* d_in, const int* in_sizes, int n_in,
                              void* d_out, int out_size, void* d_ws, size_t ws_size,
                              hipStream_t stream)
{
    const float* hidden     = (const float*)d_in[0];
    const float* in_proj_w  = (const float*)d_in[1];
    const float* conv_w     = (const float*)d_in[2];
    const float* conv_b     = (const float*)d_in[3];
    const float* x_proj_w   = (const float*)d_in[4];
    const float* dt_proj_w  = (const float*)d_in[5];
    const float* dt_proj_b  = (const float*)d_in[6];
    const float* A_log      = (const float*)d_in[7];
    const float* Dvec       = (const float*)d_in[8];
    const float* out_proj_w = (const float*)d_in[9];
    float* out = (float*)d_out;

    // ---- workspace layout (stream-ordered aliasing) ----
    const size_t MB = 1ull << 20;
    char* ws = (char*)d_ws;
    float* xz       = (float*)(ws);                 // [0,64)   MB fp32 [BL,8192]
    short* ipw_bf   = (short*)(ws + 64 * MB);       // [64,96)  in_proj_w bf16 (dead after GEMM1)
    short* x_bf     = (short*)(ws + 64 * MB);       // [64,80)  alias: x_act bf16 (conv writes)
    short* y_bf     = (short*)(ws + 80 * MB);       // [80,96)  alias: y bf16 (scan writes)
    float* dt_f32   = (float*)(ws + 96 * MB);       // [96,128) dt fp32 [BL,4096]
    float* P_part   = (float*)(ws + 96 * MB);       // [96,112) alias: x_proj partials (dead before dt)
    short* opw_bf   = (short*)(ws + 96 * MB);       // [96,112) alias: out_proj_w bf16 (cast after scan)
    short* hid_bf   = (short*)(ws + 128 * MB);      // [128,136) hidden bf16
    short* xpw_bf   = (short*)(ws + 136 * MB);      // [136,138) x_proj_w bf16 padded [256,4096]
    short* dtw_bf   = (short*)(ws + 138 * MB);      // [138,139) dt_proj_w bf16 [4096,128]
    float* xdbl_f   = (float*)(ws + 139 * MB);      // 1.25 MB  [BL,160] fp32
    short* xdbl_bf  = (short*)(ws + 141 * MB);      // 0.625 MB [BL,160] bf16

    const dim3 blk(256);

    // 1) casts for in_proj
    cast_bf16_kernel<<<dim3((BL * D_MODEL / 8 + 255) / 256), blk, 0, stream>>>(
        hidden, (uint32_t*)hid_bf, BL * D_MODEL / 8);
    cast_bf16_kernel<<<dim3((D_IN2 * D_MODEL / 8 + 255) / 256), blk, 0, stream>>>(
        in_proj_w, (uint32_t*)ipw_bf, D_IN2 * D_MODEL / 8);

    // 2) in_proj: xz[BL,8192] = hidden @ in_proj_w^T
    gemm_bf16_mfma<0><<<dim3(D_IN2 / 128, BL / 128, 1), blk, 0, stream>>>(
        hid_bf, D_MODEL, ipw_bf, D_MODEL, nullptr, xz, D_IN2, BL, D_IN2, D_MODEL, D_MODEL);

    // 3) conv + SiLU -> x_bf (overwrites dead ipw_bf region)
    conv_silu_kernel<<<dim3((BL * D_INNER) / 256), blk, 0, stream>>>(
        xz, conv_w, conv_b, x_bf);

    // 4) x_proj (split-K=8, N padded to 256): P = x_bf @ xpw^T
    hipMemsetAsync(xpw_bf, 0, (size_t)XPW_NPAD * D_INNER * 2, stream);
    cast_bf16_kernel<<<dim3((XDBL_N * D_INNER / 8 + 255) / 256), blk, 0, stream>>>(
        x_proj_w, (uint32_t*)xpw_bf, XDBL_N * D_INNER / 8);
    gemm_bf16_mfma<0><<<dim3(XPW_NPAD / 128, BL / 128, XPROJ_SPLITS), blk, 0, stream>>>(
        x_bf, D_INNER, xpw_bf, D_INNER, nullptr, P_part, XPW_NPAD,
        BL, XPW_NPAD, D_INNER, D_INNER / XPROJ_SPLITS);
    reduce_xdbl_kernel<<<dim3((BL * XDBL_N + 255) / 256), blk, 0, stream>>>(
        P_part, xdbl_f, xdbl_bf);

    // 5) dt_proj + bias + softplus -> dt_f32
    cast_bf16_kernel<<<dim3((D_INNER * DT_RANK / 8 + 255) / 256), blk, 0, stream>>>(
        dt_proj_w, (uint32_t*)dtw_bf, D_INNER * DT_RANK / 8);
    gemm_bf16_mfma<1><<<dim3(D_INNER / 128, BL / 128, 1), blk, 0, stream>>>(
        xdbl_bf, XDBL_N, dtw_bf, DT_RANK, dt_proj_b, dt_f32, D_INNER,
        BL, D_INNER, DT_RANK, DT_RANK);

    // 6) selective scan + D-skip + z-gating -> y_bf
    scan_kernel<<<dim3((BATCH * D_INNER) / 16), blk, 0, stream>>>(
        x_bf, y_bf, dt_f32, xdbl_f, xz, A_log, Dvec);

    // 7) out_proj: out = y @ out_proj_w^T  (opw cast into dead dt region)
    cast_bf16_kernel<<<dim3((D_MODEL * D_INNER / 8 + 255) / 256), blk, 0, stream>>>(
        out_proj_w, (uint32_t*)opw_bf, D_MODEL * D_INNER / 8);
    gemm_bf16_mfma<0><<<dim3(D_MODEL / 128, BL / 128, 1), blk, 0, stream>>>(
        y_bf, D_INNER, opw_bf, D_INNER, nullptr, out, D_MODEL,
        BL, D_MODEL, D_INNER, D_INNER);
}

// Round 3
// 537.887 us; speedup vs baseline: 5.3859x; 1.3741x over previous
//
#include <hip/hip_runtime.h>
#include <cstdint>
#include <cstddef>

// ---- problem constants ----
#define D_MODEL 2048
#define D_INNER 4096
#define D_IN2   8192
#define D_STATE 16
#define D_CONVK 4
#define DT_RANK 128
#define BATCH   2
#define SEQLEN  1024
#define BL      (BATCH*SEQLEN)
#define XDBL_N  (DT_RANK + 2*D_STATE)   // 160
#define XPW_NPAD 256                    // x_proj N padded to 256
#define XPROJ_SPLITS 8

// chunked-scan constants
#define NCHUNK  16
#define LCHUNK  (SEQLEN/NCHUNK)         // 64
#define CHW     (BATCH*D_INNER*D_STATE) // 131072 carry elements

typedef short  s8v  __attribute__((ext_vector_type(8)));   // 8 bf16 in 4 VGPRs
typedef float  f4v  __attribute__((ext_vector_type(4)));

__device__ __forceinline__ float softplus_f(float v) {
    return (v > 20.f) ? v : log1pf(__expf(v));
}
__device__ __forceinline__ float silu_f(float v) {
    return v / (1.f + __expf(-v));
}
__device__ __forceinline__ float bf2f(short s) {
    return __uint_as_float(((uint32_t)(uint16_t)s) << 16);
}
__device__ __forceinline__ uint16_t f2bf(float f) {   // round-to-nearest-even
    uint32_t u = __float_as_uint(f);
    return (uint16_t)((u + 0x7FFFu + ((u >> 16) & 1u)) >> 16);
}
__device__ __forceinline__ uint32_t packbf(float lo, float hi) {
    return ((uint32_t)f2bf(hi) << 16) | (uint32_t)f2bf(lo);
}
// butterfly sum over each aligned quad of lanes via DPP (no LDS pipe)
__device__ __forceinline__ float quad_sum(float p) {
    p += __int_as_float(__builtin_amdgcn_update_dpp(
            0, __float_as_int(p), 0xB1, 0xF, 0xF, true));  // quad_perm [1,0,3,2]
    p += __int_as_float(__builtin_amdgcn_update_dpp(
            0, __float_as_int(p), 0x4E, 0xF, 0xF, true));  // quad_perm [2,3,0,1]
    return p;
}

// async global->LDS, 16B per lane; LDS dest is wave-uniform base + lane*16
#define GLD16(gp, lp)                                                          \
    __builtin_amdgcn_global_load_lds(                                          \
        (const __attribute__((address_space(1))) void*)(gp),                   \
        (__attribute__((address_space(3))) void*)(lp), 16, 0, 0)

// ---- fp32 -> bf16 cast, 8 elems/thread ----
__global__ __launch_bounds__(256)
void cast_bf16_kernel(const float* __restrict__ in, uint32_t* __restrict__ out, int n8)
{
    const int i = blockIdx.x * 256 + threadIdx.x;
    if (i >= n8) return;
    const float4 a = ((const float4*)in)[i * 2];
    const float4 b = ((const float4*)in)[i * 2 + 1];
    uint4 o;
    o.x = packbf(a.x, a.y); o.y = packbf(a.z, a.w);
    o.z = packbf(b.x, b.y); o.w = packbf(b.z, b.w);
    ((uint4*)out)[i] = o;
}

// ---- bf16 MFMA GEMM: C[m,n] = sum_k A[m,k] * W[n,k]  (C = A * W^T) ----
template<int EPI>
__global__ __launch_bounds__(256)
void gemm_bf16_mfma(const short* __restrict__ A, int lda,
                    const short* __restrict__ W, int ldw,
                    const float* __restrict__ bias,
                    float* __restrict__ C, int ldc,
                    int M, int N, int K, int kchunk)
{
    __shared__ short sA[128 * 32];
    __shared__ short sW[128 * 32];

    const int tid = threadIdx.x;
    const int w   = tid >> 6;
    const int L   = tid & 63;
    const int bm  = blockIdx.y * 128;
    const int bn  = blockIdx.x * 128;
    const int k0  = blockIdx.z * kchunk;
    const int k1  = k0 + kchunk;
    C += (size_t)blockIdx.z * M * ldc;

    const int qa0 = 2 * w, qa1 = 2 * w + 1;
    const int srow = L >> 2;
    const int scol = (L & 3) * 8;

    const short* Ag0 = A + (size_t)(bm + qa0 * 16 + srow) * lda + scol;
    const short* Ag1 = A + (size_t)(bm + qa1 * 16 + srow) * lda + scol;
    const short* Wg0 = W + (size_t)(bn + qa0 * 16 + srow) * ldw + scol;
    const short* Wg1 = W + (size_t)(bn + qa1 * 16 + srow) * ldw + scol;

    const int wm = (w >> 1) * 64;
    const int wn = (w & 1) * 64;
    const int cl = L & 15;
    const int qd = L >> 4;

    f4v acc[4][4];
#pragma unroll
    for (int i = 0; i < 4; i++)
#pragma unroll
        for (int j = 0; j < 4; j++) acc[i][j] = (f4v){0.f, 0.f, 0.f, 0.f};

    for (int k = k0; k < k1; k += 32) {
        GLD16(Ag0 + k, &sA[qa0 * 512]);
        GLD16(Ag1 + k, &sA[qa1 * 512]);
        GLD16(Wg0 + k, &sW[qa0 * 512]);
        GLD16(Wg1 + k, &sW[qa1 * 512]);
        __syncthreads();

        s8v a[4], b[4];
#pragma unroll
        for (int mt = 0; mt < 4; mt++)
            a[mt] = *(const s8v*)&sA[(wm + mt * 16 + cl) * 32 + qd * 8];
#pragma unroll
        for (int nt = 0; nt < 4; nt++)
            b[nt] = *(const s8v*)&sW[(wn + nt * 16 + cl) * 32 + qd * 8];
#pragma unroll
        for (int mt = 0; mt < 4; mt++)
#pragma unroll
            for (int nt = 0; nt < 4; nt++)
                acc[mt][nt] = __builtin_amdgcn_mfma_f32_16x16x32_bf16(
                    a[mt], b[nt], acc[mt][nt], 0, 0, 0);
        __syncthreads();
    }

#pragma unroll
    for (int mt = 0; mt < 4; mt++) {
        const int row0 = bm + wm + mt * 16 + qd * 4;
#pragma unroll
        for (int nt = 0; nt < 4; nt++) {
            const int col = bn + wn + nt * 16 + cl;
#pragma unroll
            for (int r = 0; r < 4; r++) {
                float v = acc[mt][nt][r];
                if (EPI == 1) v = softplus_f(v + bias[col]);
                C[(size_t)(row0 + r) * ldc + col] = v;
            }
        }
    }
}

// ---- causal depthwise conv1d (K=4) + SiLU; reads x half of xz (fp32), writes bf16 ----
__global__ __launch_bounds__(256)
void conv_silu_kernel(const float* __restrict__ xz,
                      const float* __restrict__ cw,
                      const float* __restrict__ cb,
                      short* __restrict__ x_bf)
{
    const int idx = blockIdx.x * 256 + threadIdx.x;
    const int d  = idx & (D_INNER - 1);
    const int bl = idx >> 12;
    const int l  = bl & (SEQLEN - 1);
    const int b  = bl >> 10;
    const float* xb = xz + (size_t)b * SEQLEN * D_IN2 + d;
    float acc = cb[d];
#pragma unroll
    for (int k = 0; k < D_CONVK; k++) {
        const int ll = l + k - (D_CONVK - 1);
        if (ll >= 0) acc = fmaf(xb[(size_t)ll * D_IN2], cw[d * D_CONVK + k], acc);
    }
    x_bf[idx] = (short)f2bf(silu_f(acc));
}

// ---- reduce x_proj split-K partials -> x_dbl fp32 + bf16 ----
__global__ __launch_bounds__(256)
void reduce_xdbl_kernel(const float* __restrict__ P,
                        float* __restrict__ xf,
                        short* __restrict__ xb)
{
    const int idx = blockIdx.x * 256 + threadIdx.x;
    if (idx >= BL * XDBL_N) return;
    const int m = idx / XDBL_N;
    const int n = idx - m * XDBL_N;
    float s = 0.f;
#pragma unroll
    for (int z = 0; z < XPROJ_SPLITS; z++)
        s += P[(size_t)z * BL * XPW_NPAD + (size_t)m * XPW_NPAD + n];
    xf[idx] = s;
    xb[idx] = (short)f2bf(s);
}

// ================= chunked selective scan =================
// layout: blocks of 64 channels, 4 lanes per channel (one per 4 states).
// h_end/P/h_in: [chunk][b][d][n] fp32 (thread's 4 states = contiguous float4).

// phase 1: local scan with h_in = 0 -> h_end, P = prod(dA). chunks 0..NCHUNK-2.
__global__ __launch_bounds__(256)
void scan_phase1(const short* __restrict__ x_bf, const float* __restrict__ dt,
                 const float* __restrict__ xdbl, const float* __restrict__ A_log,
                 float* __restrict__ h_end, float* __restrict__ Pprod)
{
    const int c   = blockIdx.y;
    const int ch0 = blockIdx.x * 64;
    const int b   = ch0 >> 12;
    const int d0  = ch0 & (D_INNER - 1);
    const int tid = threadIdx.x;
    const int g   = tid >> 2;          // channel in block 0..63
    const int q   = tid & 3;           // state quad
    const int d   = d0 + g;

    const float4 Al = *(const float4*)&A_log[(d << 4) + (q << 2)];
    float An[4] = {-__expf(Al.x), -__expf(Al.y), -__expf(Al.z), -__expf(Al.w)};
    float h[4]  = {0.f, 0.f, 0.f, 0.f};
    float Pp[4] = {1.f, 1.f, 1.f, 1.f};

    __shared__ float s_x [16][68];
    __shared__ float s_dt[16][68];
    __shared__ float s_B [16][20];

    const int lt  = tid >> 4;
    const int ld4 = (tid & 15) * 4;

    for (int sub = 0; sub < LCHUNK / 16; sub++) {
        const int l0 = c * LCHUNK + sub * 16;
        const size_t bl = (size_t)(b * SEQLEN + l0 + lt);
        __syncthreads();
        {
            const short4 sx = *(const short4*)&x_bf[bl * D_INNER + d0 + ld4];
            const float4 dv = *(const float4*)&dt[bl * D_INNER + d0 + ld4];
            *(float4*)&s_x [lt][ld4] =
                make_float4(bf2f(sx.x), bf2f(sx.y), bf2f(sx.z), bf2f(sx.w));
            *(float4*)&s_dt[lt][ld4] = dv;
            if (tid < 64) {
                const int t2 = tid >> 2, k = (tid & 3) * 4;
                const size_t bl2 = (size_t)(b * SEQLEN + l0 + t2);
                *(float4*)&s_B[t2][k] =
                    *(const float4*)&xdbl[bl2 * XDBL_N + DT_RANK + k];
            }
        }
        __syncthreads();
#pragma unroll
        for (int t = 0; t < 16; t++) {
            const float xv  = s_x [t][g];
            const float dtv = s_dt[t][g];
            const float4 Bq = *(const float4*)&s_B[t][q * 4];
            const float Bv[4] = {Bq.x, Bq.y, Bq.z, Bq.w};
            const float dtx = dtv * xv;
#pragma unroll
            for (int j = 0; j < 4; j++) {
                const float dA = __expf(dtv * An[j]);
                h[j]  = fmaf(h[j], dA, dtx * Bv[j]);
                Pp[j] *= dA;
            }
        }
    }
    const size_t i0 = (size_t)c * CHW + (((size_t)(b * D_INNER + d)) << 4) + (q << 2);
    *(float4*)&h_end[i0] = make_float4(h[0], h[1], h[2], h[3]);
    *(float4*)&Pprod[i0] = make_float4(Pp[0], Pp[1], Pp[2], Pp[3]);
}

// phase 2: serial carry over chunks. one thread per (b,d,n).
__global__ __launch_bounds__(256)
void scan_phase2(const float* __restrict__ h_end, const float* __restrict__ P,
                 float* __restrict__ h_in)
{
    const int i = blockIdx.x * 256 + threadIdx.x;   // 0..CHW-1
    float carry = 0.f;
#pragma unroll
    for (int c = 0; c < NCHUNK; c++) {
        h_in[(size_t)c * CHW + i] = carry;
        if (c < NCHUNK - 1)
            carry = fmaf(P[(size_t)c * CHW + i], carry, h_end[(size_t)c * CHW + i]);
    }
}

// phase 3: local scan with true h_in; fuses D-skip + z-gating; y -> bf16.
__global__ __launch_bounds__(256)
void scan_phase3(const short* __restrict__ x_bf, short* __restrict__ y_bf,
                 const float* __restrict__ dt, const float* __restrict__ xdbl,
                 const float* __restrict__ xz, const float* __restrict__ A_log,
                 const float* __restrict__ Dvec, const float* __restrict__ h_in)
{
    const int c   = blockIdx.y;
    const int ch0 = blockIdx.x * 64;
    const int b   = ch0 >> 12;
    const int d0  = ch0 & (D_INNER - 1);
    const int tid = threadIdx.x;
    const int g   = tid >> 2;
    const int q   = tid & 3;
    const int d   = d0 + g;

    const float4 Al = *(const float4*)&A_log[(d << 4) + (q << 2)];
    float An[4] = {-__expf(Al.x), -__expf(Al.y), -__expf(Al.z), -__expf(Al.w)};
    const float Dd = Dvec[d];
    const float4 h4 = *(const float4*)
        &h_in[(size_t)c * CHW + (((size_t)(b * D_INNER + d)) << 4) + (q << 2)];
    float h[4] = {h4.x, h4.y, h4.z, h4.w};

    __shared__ float s_x [16][68];
    __shared__ float s_dt[16][68];
    __shared__ float s_z [16][68];
    __shared__ float s_B [16][20];
    __shared__ float s_C [16][20];

    const int lt  = tid >> 4;
    const int ld4 = (tid & 15) * 4;

    for (int sub = 0; sub < LCHUNK / 16; sub++) {
        const int l0 = c * LCHUNK + sub * 16;
        const size_t bl = (size_t)(b * SEQLEN + l0 + lt);
        __syncthreads();
        {
            const short4 sx = *(const short4*)&x_bf[bl * D_INNER + d0 + ld4];
            const float4 dv = *(const float4*)&dt[bl * D_INNER + d0 + ld4];
            const float4 zv = *(const float4*)&xz[bl * D_IN2 + D_INNER + d0 + ld4];
            *(float4*)&s_x [lt][ld4] =
                make_float4(bf2f(sx.x), bf2f(sx.y), bf2f(sx.z), bf2f(sx.w));
            *(float4*)&s_dt[lt][ld4] = dv;
            *(float4*)&s_z [lt][ld4] = zv;
            if (tid < 128) {
                const int t2 = (tid & 63) >> 2, k = (tid & 3) * 4;
                const size_t bl2 = (size_t)(b * SEQLEN + l0 + t2);
                const int off = (tid < 64) ? 0 : D_STATE;   // wave-uniform
                const float4 v =
                    *(const float4*)&xdbl[bl2 * XDBL_N + DT_RANK + off + k];
                if (tid < 64) *(float4*)&s_B[t2][k] = v;
                else          *(float4*)&s_C[t2][k] = v;
            }
        }
        __syncthreads();
        const size_t orow = (size_t)(b * SEQLEN + l0);
#pragma unroll
        for (int t = 0; t < 16; t++) {
            const float xv  = s_x [t][g];
            const float dtv = s_dt[t][g];
            const float4 Bq = *(const float4*)&s_B[t][q * 4];
            const float4 Cq = *(const float4*)&s_C[t][q * 4];
            const float Bv[4] = {Bq.x, Bq.y, Bq.z, Bq.w};
            const float Cv[4] = {Cq.x, Cq.y, Cq.z, Cq.w};
            const float dtx = dtv * xv;
            float p = 0.f;
#pragma unroll
            for (int j = 0; j < 4; j++) {
                const float dA = __expf(dtv * An[j]);
                h[j] = fmaf(h[j], dA, dtx * Bv[j]);
                p = fmaf(h[j], Cv[j], p);
            }
            p = quad_sum(p);
            if (q == 0) {
                const float yv = fmaf(xv, Dd, p) * silu_f(s_z[t][g]);
                y_bf[(orow + t) * D_INNER + d] = (short)f2bf(yv);
            }
        }
    }
}

extern "C" void kernel_launch(void* const* d_in, const int* in_sizes, int n_in,
                              void* d_out, int out_size, void* d_ws, size_t ws_size,
                              hipStream_t stream)
{
    const float* hidden     = (const float*)d_in[0];
    const float* in_proj_w  = (const float*)d_in[1];
    const float* conv_w     = (const float*)d_in[2];
    const float* conv_b     = (const float*)d_in[3];
    const float* x_proj_w   = (const float*)d_in[4];
    const float* dt_proj_w  = (const float*)d_in[5];
    const float* dt_proj_b  = (const float*)d_in[6];
    const float* A_log      = (const float*)d_in[7];
    const float* Dvec       = (const float*)d_in[8];
    const float* out_proj_w = (const float*)d_in[9];
    float* out = (float*)d_out;

    // ---- workspace layout (stream-ordered aliasing) ----
    const size_t MB = 1ull << 20;
    char* ws = (char*)d_ws;
    float* xz       = (float*)(ws);                 // [0,64)   fp32 [BL,8192]
    short* ipw_bf   = (short*)(ws + 64 * MB);       // [64,96)  in_proj_w bf16 (dead after GEMM1)
    short* x_bf     = (short*)(ws + 64 * MB);       // [64,80)  alias: x_act bf16
    short* y_bf     = (short*)(ws + 80 * MB);       // [80,96)  alias: y bf16 (phase3 writes)
    float* h_end    = (float*)(ws + 80 * MB);       // [80,88)  alias: chunk h_end (dead pre-phase3)
    float* Pbuf     = (float*)(ws + 88 * MB);       // [88,96)  alias: chunk decay products
    float* dt_f32   = (float*)(ws + 96 * MB);       // [96,128) dt fp32 [BL,4096]
    float* P_part   = (float*)(ws + 96 * MB);       // alias: x_proj partials (dead before dt)
    short* opw_bf   = (short*)(ws + 96 * MB);       // alias: out_proj_w bf16 (cast after scan)
    float* h_in     = (float*)(ws + 128 * MB);      // [128,136.4) alias over dead hid_bf/xpw head
    short* hid_bf   = (short*)(ws + 128 * MB);      // [128,136) hidden bf16 (dead after GEMM1)
    short* xpw_bf   = (short*)(ws + 136 * MB);      // [136,138) x_proj_w bf16 (dead after x_proj)
    short* dtw_bf   = (short*)(ws + 138 * MB);      // [138,139) dt_proj_w bf16
    float* xdbl_f   = (float*)(ws + 139 * MB);      // 1.25 MB  [BL,160] fp32
    short* xdbl_bf  = (short*)(ws + 141 * MB);      // 0.625 MB [BL,160] bf16

    const dim3 blk(256);

    // 1) casts for in_proj
    cast_bf16_kernel<<<dim3((BL * D_MODEL / 8 + 255) / 256), blk, 0, stream>>>(
        hidden, (uint32_t*)hid_bf, BL * D_MODEL / 8);
    cast_bf16_kernel<<<dim3((D_IN2 * D_MODEL / 8 + 255) / 256), blk, 0, stream>>>(
        in_proj_w, (uint32_t*)ipw_bf, D_IN2 * D_MODEL / 8);

    // 2) in_proj: xz[BL,8192] = hidden @ in_proj_w^T
    gemm_bf16_mfma<0><<<dim3(D_IN2 / 128, BL / 128, 1), blk, 0, stream>>>(
        hid_bf, D_MODEL, ipw_bf, D_MODEL, nullptr, xz, D_IN2, BL, D_IN2, D_MODEL, D_MODEL);

    // 3) conv + SiLU -> x_bf
    conv_silu_kernel<<<dim3((BL * D_INNER) / 256), blk, 0, stream>>>(
        xz, conv_w, conv_b, x_bf);

    // 4) x_proj (split-K=8, N padded to 256)
    hipMemsetAsync(xpw_bf, 0, (size_t)XPW_NPAD * D_INNER * 2, stream);
    cast_bf16_kernel<<<dim3((XDBL_N * D_INNER / 8 + 255) / 256), blk, 0, stream>>>(
        x_proj_w, (uint32_t*)xpw_bf, XDBL_N * D_INNER / 8);
    gemm_bf16_mfma<0><<<dim3(XPW_NPAD / 128, BL / 128, XPROJ_SPLITS), blk, 0, stream>>>(
        x_bf, D_INNER, xpw_bf, D_INNER, nullptr, P_part, XPW_NPAD,
        BL, XPW_NPAD, D_INNER, D_INNER / XPROJ_SPLITS);
    reduce_xdbl_kernel<<<dim3((BL * XDBL_N + 255) / 256), blk, 0, stream>>>(
        P_part, xdbl_f, xdbl_bf);

    // 5) dt_proj + bias + softplus -> dt_f32
    cast_bf16_kernel<<<dim3((D_INNER * DT_RANK / 8 + 255) / 256), blk, 0, stream>>>(
        dt_proj_w, (uint32_t*)dtw_bf, D_INNER * DT_RANK / 8);
    gemm_bf16_mfma<1><<<dim3(D_INNER / 128, BL / 128, 1), blk, 0, stream>>>(
        xdbl_bf, XDBL_N, dtw_bf, DT_RANK, dt_proj_b, dt_f32, D_INNER,
        BL, D_INNER, DT_RANK, DT_RANK);

    // 6) chunked selective scan
    scan_phase1<<<dim3(BATCH * D_INNER / 64, NCHUNK - 1), blk, 0, stream>>>(
        x_bf, dt_f32, xdbl_f, A_log, h_end, Pbuf);
    scan_phase2<<<dim3(CHW / 256), blk, 0, stream>>>(h_end, Pbuf, h_in);
    scan_phase3<<<dim3(BATCH * D_INNER / 64, NCHUNK), blk, 0, stream>>>(
        x_bf, y_bf, dt_f32, xdbl_f, xz, A_log, Dvec, h_in);

    // 7) out_proj: out = y @ out_proj_w^T
    cast_bf16_kernel<<<dim3((D_MODEL * D_INNER / 8 + 255) / 256), blk, 0, stream>>>(
        out_proj_w, (uint32_t*)opw_bf, D_MODEL * D_INNER / 8);
    gemm_bf16_mfma<0><<<dim3(D_MODEL / 128, BL / 128, 1), blk, 0, stream>>>(
        y_bf, D_INNER, opw_bf, D_INNER, nullptr, out, D_MODEL,
        BL, D_MODEL, D_INNER, D_INNER);
}